// Round 3
// baseline (1134.617 us; speedup 1.0000x reference)
//
#include <hip/hip_runtime.h>
#include <hip/hip_bf16.h>

// Problem constants (from the reference):
//   LEVELS=8, DICT_SIZE=256, FEAT_DIM=128, NUM_WORDS=100000, N=100000
// inputs: idx (int32 [N]), dictionary (f32 [L,K,D]), feats (f32 [L,NW,K])
// output: f32 [N, L*D]

constexpr int L_  = 8;
constexpr int K_  = 256;
constexpr int D_  = 128;
constexpr int NW_ = 100000;
constexpr int N_  = 100000;

typedef float v2f __attribute__((ext_vector_type(2)));

__device__ __forceinline__ int wave_argmax256(const float4 v, const int lane) {
    // local argmax over this lane's 4 elements, first-index tie-break
    float best = v.x; int bi = lane * 4;
    if (v.y > best) { best = v.y; bi = lane * 4 + 1; }
    if (v.z > best) { best = v.z; bi = lane * 4 + 2; }
    if (v.w > best) { best = v.w; bi = lane * 4 + 3; }
    // 64-lane butterfly argmax (first-index tie-break, matches jnp.argmax)
    #pragma unroll
    for (int m = 1; m < 64; m <<= 1) {
        float ov = __shfl_xor(best, m, 64);
        int   oi = __shfl_xor(bi,   m, 64);
        if (ov > best || (ov == best && oi < bi)) { best = ov; bi = oi; }
    }
    return bi;   // identical across the wave
}

__global__ __launch_bounds__(256) void codebook_kernel(
    const int* __restrict__ idx,
    const float* __restrict__ dict,
    const float* __restrict__ feats,
    float* __restrict__ out) {

    const int lane  = threadIdx.x & 63;
    const int wib   = threadIdx.x >> 6;                 // wave index in block
    const int wpb   = blockDim.x >> 6;                  // waves per block (4)
    const int gwave = blockIdx.x * wpb + wib;
    const int nwave = gridDim.x * wpb;

    // Level-major traversal: at any instant all resident waves touch one
    // level's 102.4 MB feats slab -> duplicate idx rows hit L3, not HBM.
    for (int l = 0; l < L_; ++l) {
        const float* __restrict__ fl = feats + (size_t)l * NW_ * K_;
        const float* __restrict__ dl = dict  + (size_t)l * K_ * D_;

        // Two rows per iteration: both 1 KB feats loads issued before either
        // reduce -> 2x memory-level parallelism per wave (latency hiding).
        for (int n0 = gwave * 2; n0 < N_; n0 += nwave * 2) {
            const int nu = __builtin_amdgcn_readfirstlane(n0);
            const int w0 = idx[nu];                     // wave-uniform (s_load)
            const int w1 = idx[nu + 1];                 // N_ is even -> in range

            const float4 va = *reinterpret_cast<const float4*>(
                fl + (size_t)w0 * K_ + lane * 4);
            const float4 vb = *reinterpret_cast<const float4*>(
                fl + (size_t)w1 * K_ + lane * 4);

            const int ca = wave_argmax256(va, lane);
            const int cb = wave_argmax256(vb, lane);

            // dictionary rows: 512 B each, 1 MB total table -> L2-resident
            const v2f da = *reinterpret_cast<const v2f*>(
                dl + (size_t)ca * D_ + lane * 2);
            const v2f db = *reinterpret_cast<const v2f*>(
                dl + (size_t)cb * D_ + lane * 2);

            // output rows n0, n0+1, level-l slice; streaming stores
            v2f* oa = reinterpret_cast<v2f*>(
                out + (size_t)n0 * (L_ * D_) + l * D_ + lane * 2);
            v2f* ob = reinterpret_cast<v2f*>(
                out + (size_t)(n0 + 1) * (L_ * D_) + l * D_ + lane * 2);
            __builtin_nontemporal_store(da, oa);
            __builtin_nontemporal_store(db, ob);
        }
    }
}

extern "C" void kernel_launch(void* const* d_in, const int* in_sizes, int n_in,
                              void* d_out, int out_size, void* d_ws, size_t ws_size,
                              hipStream_t stream) {
    const int*   idx   = (const int*)d_in[0];
    const float* dict  = (const float*)d_in[1];
    const float* feats = (const float*)d_in[2];
    float*       out   = (float*)d_out;

    // 2048 blocks x 256 threads = 8192 waves (8 blocks/CU); each wave does
    // ~6 double-row iterations per level.
    dim3 grid(2048), block(256);
    hipLaunchKernelGGL(codebook_kernel, grid, block, 0, stream,
                       idx, dict, feats, out);
}